// Round 9
// baseline (256.920 us; speedup 1.0000x reference)
//
#include <hip/hip_runtime.h>
#include <hip/hip_bf16.h>

// AudioCrossAttention on MI355X (gfx950).
// cvt(f32->bf16) | gemm_qkv 128x128 single-buf (Q prescaled; K+lrope; V->V^T) |
// flash-attn 32x32x16 swapped-QK^T, in-register P (cvt_pk+permlane32_swap) |
// gemm_out 64x128 single-buf. T1 XCD swizzle on all tiled kernels.
// NOTE: permlane32_swap via inline asm is ONLY used where the two operands are
// provably-distinct SSA values (E/O network). Identical-value combines use
// __shfl_xor(,32) — two "+v" operands holding the same value may be allocated
// to ONE register, turning the swap into a destructive half-rotate (r8 bug).

typedef short s16x8 __attribute__((ext_vector_type(8)));
typedef float f32x4 __attribute__((ext_vector_type(4)));
typedef float f32x16 __attribute__((ext_vector_type(16)));
typedef unsigned uintx4 __attribute__((ext_vector_type(4)));

__device__ __forceinline__ short f2bf(float f) {
    unsigned u = __float_as_uint(f);
    u = u + 0x7fffu + ((u >> 16) & 1u);   // RNE
    return (short)(u >> 16);
}

__device__ __forceinline__ unsigned cvtpk(float lo, float hi) {
    unsigned r;
    asm volatile("v_cvt_pk_bf16_f32 %0, %1, %2" : "=v"(r) : "v"(lo), "v"(hi));
    return r;
}

// a <- (a.lo32, b.lo32); b <- (a.hi32, b.hi32).  Operands MUST be distinct values.
#define PLSWAP(a, b) asm volatile("v_permlane32_swap_b32 %0, %1" : "+v"(a), "+v"(b))

#define GLDS16(g, l)                                                          \
    __builtin_amdgcn_global_load_lds(                                         \
        (const __attribute__((address_space(1))) void*)(g),                   \
        (__attribute__((address_space(3))) void*)(l), 16, 0, 0)

// ---------------------------------------------------------------------------
__global__ __launch_bounds__(256)
void cvt_all(const float* __restrict__ vis, const float* __restrict__ aud,
             const float* __restrict__ Wq, const float* __restrict__ Wk,
             const float* __restrict__ Wv, const float* __restrict__ Wo,
             short* __restrict__ visB, short* __restrict__ audB,
             short* __restrict__ WqB, short* __restrict__ WkB,
             short* __restrict__ WvB, short* __restrict__ WoB)
{
    const int bid = blockIdx.x;
    const float* src; short* dst; int vec0;
    if (bid < 2048)      { src = vis; dst = visB; vec0 = bid * 256; }
    else if (bid < 4096) { src = aud; dst = audB; vec0 = (bid - 2048) * 256; }
    else {
        const int r = bid - 4096, w = r >> 9, lb = r & 511;
        vec0 = lb * 256;
        if      (w == 0) { src = Wq; dst = WqB; }
        else if (w == 1) { src = Wk; dst = WkB; }
        else if (w == 2) { src = Wv; dst = WvB; }
        else             { src = Wo; dst = WoB; }
    }
    const int i = (vec0 + threadIdx.x) * 8;
    float4 a = *(const float4*)(src + i);
    float4 b = *(const float4*)(src + i + 4);
    s16x8 o;
    o[0]=f2bf(a.x); o[1]=f2bf(a.y); o[2]=f2bf(a.z); o[3]=f2bf(a.w);
    o[4]=f2bf(b.x); o[5]=f2bf(b.y); o[6]=f2bf(b.z); o[7]=f2bf(b.w);
    *(s16x8*)(dst + i) = o;
}

// ---------------------------------------------------------------------------
// Fused Q/K/V projection, 128x128 tile, BK=64, SINGLE-buffer LDS (m97 form),
// grid 768 blocks -> 3 blocks/CU co-resident. T1 XCD swizzle (nwg=768).
// z: 0=Q (prescaled 0.125), 1=K (+lrope), 2=V (writes V^T [bh][64 d][2048 kv]).
__global__ __launch_bounds__(256)
void gemm_qkv(const short* __restrict__ visB, const short* __restrict__ audB,
              const short* __restrict__ WqB, const short* __restrict__ WkB,
              const short* __restrict__ WvB,
              const float* __restrict__ bq, const float* __restrict__ bk,
              const float* __restrict__ bv,
              short* __restrict__ outQ, short* __restrict__ outK,
              short* __restrict__ outVt,
              const int* __restrict__ labels, const float* __restrict__ lemb)
{
    __shared__ __align__(16) short SM[16384];   // As 8192 | Bs 8192 (32 KB)
    short* As = SM;
    short* Bs = SM + 8192;
    const int tid  = threadIdx.x;
    const int lane = tid & 63;
    const int wid  = tid >> 6;
    const int q15  = lane & 15;
    const int hi   = lane >> 4;
    // T1: dispatch-linear id -> contiguous chunk per XCD
    const int lid = blockIdx.x + 8 * blockIdx.y + 256 * blockIdx.z;
    const int wk  = (lid & 7) * 96 + (lid >> 3);
    const int z   = wk >> 8;
    const int rowBase = ((wk >> 3) & 31) * 128;
    const int colBase = (wk & 7) * 128;
    const int wr = (wid >> 1) * 64;
    const int wc = (wid & 1) * 64;
    const short* X = (z == 0) ? visB : audB;
    const short* W = (z == 0) ? WqB : (z == 1) ? WkB : WvB;
    const float* bias = (z == 0) ? bq : (z == 1) ? bk : bv;

    f32x4 acc[4][4] = {};

    for (int t = 0; t < 16; ++t) {
        const int k0 = t * 64;
        __syncthreads();   // all waves done reading previous tile
        #pragma unroll
        for (int c = 0; c < 4; ++c) {
            const int u   = (wid * 4 + c) * 64 + lane;
            const int row = u >> 3;
            const int k8a = (u & 7) ^ (row & 7);
            GLDS16(X + (size_t)(rowBase + row) * 1024 + k0 + k8a * 8,
                   As + (wid * 4 + c) * 512);
            GLDS16(W + (size_t)(colBase + row) * 1024 + k0 + k8a * 8,
                   Bs + (wid * 4 + c) * 512);
        }
        __syncthreads();   // vmcnt drained: tile resident
        #pragma unroll
        for (int ks = 0; ks < 2; ++ks) {
            const int kb = ks * 64 + (hi << 4);
            s16x8 af[4], bfv[4];
            #pragma unroll
            for (int m = 0; m < 4; ++m) {
                const int row = wr + m * 16 + q15;
                af[m] = *(const s16x8*)((const char*)As + row * 128 + (kb ^ ((row & 7) << 4)));
            }
            #pragma unroll
            for (int n = 0; n < 4; ++n) {
                const int row = wc + n * 16 + q15;
                bfv[n] = *(const s16x8*)((const char*)Bs + row * 128 + (kb ^ ((row & 7) << 4)));
            }
            #pragma unroll
            for (int m = 0; m < 4; ++m)
                #pragma unroll
                for (int n = 0; n < 4; ++n)
                    acc[m][n] = __builtin_amdgcn_mfma_f32_16x16x32_bf16(af[m], bfv[n], acc[m][n], 0, 0, 0);
        }
    }

    if (z == 2) {
        __syncthreads();   // all waves done with SM before scratch reuse
        // Per-wave transpose scratch 64 hd x 64 kv (8 KB each): one head.
        char* tb = (char*)SM + wid * 8192;
        const int b  = rowBase >> 11;
        const int h  = (colBase + wc) >> 6;
        const int kvbase = (rowBase & 2047) + wr;
        #pragma unroll
        for (int m = 0; m < 4; ++m) {
            #pragma unroll
            for (int r = 0; r < 4; ++r) {
                const int kvl = m * 16 + hi * 4 + r;
                #pragma unroll
                for (int n = 0; n < 4; ++n) {
                    const int hd = n * 16 + q15;
                    const float v = acc[m][n][r] + bias[colBase + wc + hd];
                    *(short*)(tb + hd * 128 + ((kvl * 2) ^ ((hd & 7) << 4))) = f2bf(v);
                }
            }
        }
        asm volatile("s_waitcnt lgkmcnt(0)" ::: "memory");  // wave-local
        #pragma unroll
        for (int c = 0; c < 8; ++c) {
            const int u  = c * 64 + lane;
            const int hd = u >> 3;
            const int kc = u & 7;
            s16x8 vv = *(const s16x8*)(tb + hd * 128 + ((kc * 16) ^ ((hd & 7) << 4)));
            *(s16x8*)(outVt + ((size_t)(b * 16 + h) * 64 + hd) * 2048 + kvbase + kc * 8) = vv;
        }
    } else {
        short* Co = (z == 0) ? outQ : outK;
        #pragma unroll
        for (int m = 0; m < 4; ++m) {
            #pragma unroll
            for (int r = 0; r < 4; ++r) {
                const int grow = rowBase + wr + m * 16 + hi * 4 + r;
                #pragma unroll
                for (int n = 0; n < 4; ++n) {
                    const int gcol = colBase + wc + n * 16 + q15;
                    float v = acc[m][n][r] + bias[gcol];
                    if (z == 0) {
                        v *= 0.125f;                      // fold hd^-0.5 into Q
                    } else {
                        const int bb = grow >> 11;
                        const int ss = grow & 2047;
                        const int hd = gcol & 63;
                        const int fi = hd & 31;
                        const float ang = (float)ss * __expf((float)fi * (-9.210340371976184f / 32.0f));
                        const float tr  = (hd < 32) ? sinf(ang) : cosf(ang);
                        v += tr * lemb[labels[bb] * 64 + hd];
                    }
                    Co[(size_t)grow * 1024 + gcol] = f2bf(v);
                }
            }
        }
    }
}

// ---------------------------------------------------------------------------
// Output projection, 64x128 tile, single-buffer, grid 512, T1 swizzle.
__global__ __launch_bounds__(256)
void gemm_out(const short* __restrict__ X, const short* __restrict__ W,
              const float* __restrict__ bias, float* __restrict__ Cf)
{
    __shared__ __align__(16) short SM[12288];   // As 4096 | Bs 8192 (24 KB)
    short* As = SM;
    short* Bs = SM + 4096;
    const int tid  = threadIdx.x;
    const int lane = tid & 63;
    const int wid  = tid >> 6;
    const int q15  = lane & 15;
    const int hi   = lane >> 4;
    const int lid = blockIdx.x + 8 * blockIdx.y;
    const int wk  = (lid & 7) * 64 + (lid >> 3);
    const int rowBase = (wk >> 3) * 64;
    const int colBase = (wk & 7) * 128;
    const int wr = (wid >> 1) * 32;
    const int wc = (wid & 1) * 64;

    f32x4 acc[2][4] = {};

    for (int t = 0; t < 16; ++t) {
        const int k0 = t * 64;
        __syncthreads();
        #pragma unroll
        for (int c = 0; c < 2; ++c) {
            const int u   = c * 256 + tid;
            const int row = u >> 3;
            const int k8a = (u & 7) ^ (row & 7);
            GLDS16(X + (size_t)(rowBase + row) * 1024 + k0 + k8a * 8,
                   As + (c * 256 + wid * 64) * 8);
        }
        #pragma unroll
        for (int c = 0; c < 4; ++c) {
            const int u   = c * 256 + tid;
            const int row = u >> 3;
            const int k8a = (u & 7) ^ (row & 7);
            GLDS16(W + (size_t)(colBase + row) * 1024 + k0 + k8a * 8,
                   Bs + (c * 256 + wid * 64) * 8);
        }
        __syncthreads();
        #pragma unroll
        for (int ks = 0; ks < 2; ++ks) {
            const int kb = ks * 64 + (hi << 4);
            s16x8 af[2], bfv[4];
            #pragma unroll
            for (int m = 0; m < 2; ++m) {
                const int row = wr + m * 16 + q15;
                af[m] = *(const s16x8*)((const char*)As + row * 128 + (kb ^ ((row & 7) << 4)));
            }
            #pragma unroll
            for (int n = 0; n < 4; ++n) {
                const int row = wc + n * 16 + q15;
                bfv[n] = *(const s16x8*)((const char*)Bs + row * 128 + (kb ^ ((row & 7) << 4)));
            }
            #pragma unroll
            for (int m = 0; m < 2; ++m)
                #pragma unroll
                for (int n = 0; n < 4; ++n)
                    acc[m][n] = __builtin_amdgcn_mfma_f32_16x16x32_bf16(af[m], bfv[n], acc[m][n], 0, 0, 0);
        }
    }

    #pragma unroll
    for (int m = 0; m < 2; ++m) {
        #pragma unroll
        for (int r = 0; r < 4; ++r) {
            const int grow = rowBase + wr + m * 16 + hi * 4 + r;
            #pragma unroll
            for (int n = 0; n < 4; ++n) {
                const int gcol = colBase + wc + n * 16 + q15;
                Cf[(size_t)grow * 1024 + gcol] = acc[m][n][r] + bias[gcol];
            }
        }
    }
}

// ---------------------------------------------------------------------------
// Flash attention, 32x32x16 swapped QK^T, fully in-register P (T12).
// grid (16 qt, 32 bh) with T1 swizzle; 4 waves x 32 q-rows = 128 q/block.
// Lane: q = lane&31 for S; h = lane>>5 selects kv/d half-chunks.
__global__ __launch_bounds__(256)
void attn_fwd(const short* __restrict__ Q, const short* __restrict__ K,
              const short* __restrict__ Vt, short* __restrict__ AO)
{
    __shared__ __align__(16) short Ks[2][64 * 64];
    __shared__ __align__(16) short Vs[2][64 * 64];
    const int tid  = threadIdx.x;
    const int lane = tid & 63;
    const int wid  = tid >> 6;
    const int l31  = lane & 31;
    const int h    = lane >> 5;
    const int lid = blockIdx.x + 16 * blockIdx.y;          // nwg = 512
    const int wk  = (lid & 7) * 64 + (lid >> 3);           // T1: 4 bh per XCD
    const int qt  = wk & 15;
    const int bh  = wk >> 4;
    const int b   = bh >> 4, hh = bh & 15;
    const int qrow0 = b * 2048 + qt * 128 + wid * 32;      // wave's 32 q-rows
    const int hoff  = hh * 64;
    const short* Kb = K + (size_t)b * 2048 * 1024 + hoff;
    const short* Vb = Vt + (size_t)bh * 64 * 2048;

    // Q in regs: row q = l31, d-chunks {st*16 + h*8 .. +7}, st=0..3 (16 VGPR)
    s16x8 qf[4];
    {
        const short* qp = Q + (size_t)(qrow0 + l31) * 1024 + hoff + h * 8;
        #pragma unroll
        for (int st = 0; st < 4; ++st) qf[st] = *(const s16x8*)(qp + st * 16);
    }

    auto stage = [&](int buf, int kv0) {
        #pragma unroll
        for (int c = 0; c < 2; ++c) {
            const int ub  = c * 256 + wid * 64;
            const int u   = ub + lane;
            const int row = u >> 3;
            const int k8  = (u & 7) ^ (row & 7);
            GLDS16(Kb + (size_t)(kv0 + row) * 1024 + k8 * 8, &Ks[buf][ub * 8]);
            GLDS16(Vb + (size_t)row * 2048 + kv0 + k8 * 8,   &Vs[buf][ub * 8]);
        }
    };

    float mrun = -1e30f, lsum = 0.f;
    f32x16 o0 = {}, o1 = {};     // O[q-regs][d = l31 + 32*db]

    stage(0, 0);
    __syncthreads();

    for (int t = 0; t < 32; ++t) {
        const int cur = t & 1;
        if (t < 31) stage(cur ^ 1, (t + 1) * 64);

        // S^T = K · Q^T : sA/sB = kv-blocks 0/1. Lane: q = l31 (col),
        // kv = (reg&3)+8*(reg>>2)+4h (+32 for sB).
        f32x16 sA = {}, sB = {};
        #pragma unroll
        for (int st = 0; st < 4; ++st) {
            const int kb = st * 32 + h * 16;
            const int sw = (l31 & 7) << 4;
            s16x8 a0 = *(const s16x8*)((const char*)&Ks[cur][0] + l31 * 128 + (kb ^ sw));
            s16x8 a1 = *(const s16x8*)((const char*)&Ks[cur][0] + (32 + l31) * 128 + (kb ^ sw));
            sA = __builtin_amdgcn_mfma_f32_32x32x16_bf16(a0, qf[st], sA, 0, 0, 0);
            sB = __builtin_amdgcn_mfma_f32_32x32x16_bf16(a1, qf[st], sB, 0, 0, 0);
        }

        // per-lane max over own 32 values; defer-max (THR=8)
        float pm = sA[0];
        #pragma unroll
        for (int r = 1; r < 16; ++r) pm = fmaxf(pm, sA[r]);
        #pragma unroll
        for (int r = 0; r < 16; ++r) pm = fmaxf(pm, sB[r]);
        if (__any(pm > mrun + 8.0f)) {
            // cross-half combine via shfl_xor (NOT permlane on identical values)
            pm = fmaxf(pm, __shfl_xor(pm, 32));
            const float mn = fmaxf(mrun, pm);
            const float al = __expf(mrun - mn);
            mrun = mn;
            lsum *= al;
            #pragma unroll
            for (int reg = 0; reg < 16; ++reg) {
                const int qsrc = ((reg & 3) + 8 * (reg >> 2)) + 4 * h;
                const float aq = __shfl(al, qsrc);
                o0[reg] *= aq;
                o1[reg] *= aq;
            }
        }

        // exp -> pack (cvt_pk) -> cross-half exchange (permlane32_swap) -> PV
        #pragma unroll
        for (int ks = 0; ks < 4; ++ks) {
            float p0, p1, p2, p3, p4, p5, p6, p7;
            if (ks == 0) {
                p0=__expf(sA[0]-mrun); p1=__expf(sA[1]-mrun); p2=__expf(sA[2]-mrun); p3=__expf(sA[3]-mrun);
                p4=__expf(sA[4]-mrun); p5=__expf(sA[5]-mrun); p6=__expf(sA[6]-mrun); p7=__expf(sA[7]-mrun);
            } else if (ks == 1) {
                p0=__expf(sA[8]-mrun); p1=__expf(sA[9]-mrun); p2=__expf(sA[10]-mrun); p3=__expf(sA[11]-mrun);
                p4=__expf(sA[12]-mrun); p5=__expf(sA[13]-mrun); p6=__expf(sA[14]-mrun); p7=__expf(sA[15]-mrun);
            } else if (ks == 2) {
                p0=__expf(sB[0]-mrun); p1=__expf(sB[1]-mrun); p2=__expf(sB[2]-mrun); p3=__expf(sB[3]-mrun);
                p4=__expf(sB[4]-mrun); p5=__expf(sB[5]-mrun); p6=__expf(sB[6]-mrun); p7=__expf(sB[7]-mrun);
            } else {
                p0=__expf(sB[8]-mrun); p1=__expf(sB[9]-mrun); p2=__expf(sB[10]-mrun); p3=__expf(sB[11]-mrun);
                p4=__expf(sB[12]-mrun); p5=__expf(sB[13]-mrun); p6=__expf(sB[14]-mrun); p7=__expf(sB[15]-mrun);
            }
            lsum += ((p0 + p1) + (p2 + p3)) + ((p4 + p5) + (p6 + p7));
            unsigned E0 = cvtpk(p0, p1), E1 = cvtpk(p2, p3);
            unsigned O0 = cvtpk(p4, p5), O1 = cvtpk(p6, p7);
            PLSWAP(E0, O0);   // h=0: kv 0-7 of this 16-slice; h=1: kv 8-15
            PLSWAP(E1, O1);
            uintx4 fr = {E0, E1, O0, O1};
            s16x8 pa = __builtin_bit_cast(s16x8, fr);

            const int kb = ks * 32 + h * 16;
            const int sw = (l31 & 7) << 4;
            s16x8 vb0 = *(const s16x8*)((const char*)&Vs[cur][0] + l31 * 128 + (kb ^ sw));
            s16x8 vb1 = *(const s16x8*)((const char*)&Vs[cur][0] + (32 + l31) * 128 + (kb ^ sw));
            o0 = __builtin_amdgcn_mfma_f32_32x32x16_bf16(pa, vb0, o0, 0, 0, 0);
            o1 = __builtin_amdgcn_mfma_f32_32x32x16_bf16(pa, vb1, o1, 0, 0, 0);
        }
        __syncthreads();   // drains prefetch vmcnt; all reads of cur done
    }

    // final: full-row l via shfl_xor, redistribute 1/l to O layout
    const float ltot = lsum + __shfl_xor(lsum, 32);
    const float inv = 1.0f / ltot;
    #pragma unroll
    for (int reg = 0; reg < 16; ++reg) {
        const int crow = (reg & 3) + 8 * (reg >> 2) + 4 * h;
        const float iq = __shfl(inv, crow);
        const int grow = qrow0 + crow;
        AO[(size_t)grow * 1024 + hoff + l31]      = f2bf(o0[reg] * iq);
        AO[(size_t)grow * 1024 + hoff + 32 + l31] = f2bf(o1[reg] * iq);
    }
}

extern "C" void kernel_launch(void* const* d_in, const int* in_sizes, int n_in,
                              void* d_out, int out_size, void* d_ws, size_t ws_size,
                              hipStream_t stream) {
    const float* vis    = (const float*)d_in[0];
    const float* aud    = (const float*)d_in[1];
    const int*   labels = (const int*)d_in[2];
    const float* Wq = (const float*)d_in[3];  const float* bq = (const float*)d_in[4];
    const float* Wk = (const float*)d_in[5];  const float* bk = (const float*)d_in[6];
    const float* Wv = (const float*)d_in[7];  const float* bv = (const float*)d_in[8];
    const float* Wo = (const float*)d_in[9];  const float* bo = (const float*)d_in[10];
    const float* lemb = (const float*)d_in[11];

    short* wsQ   = (short*)d_ws;              // 4M shorts each
    short* wsK   = wsQ  + 4194304;
    short* wsVt  = wsK  + 4194304;            // [32 bh][64 d][2048 kv]
    short* wsAO  = wsVt + 4194304;
    short* visB  = wsAO + 4194304;
    short* audB  = visB + 4194304;
    short* WqB   = audB + 4194304;
    short* WkB   = WqB  + 1048576;
    short* WvB   = WkB  + 1048576;
    short* WoB   = WvB  + 1048576;
    float* out   = (float*)d_out;

    cvt_all<<<6144, 256, 0, stream>>>(vis, aud, Wq, Wk, Wv, Wo,
                                      visB, audB, WqB, WkB, WvB, WoB);
    gemm_qkv<<<dim3(8, 32, 3), 256, 0, stream>>>(visB, audB, WqB, WkB, WvB,
                                                 bq, bk, bv, wsQ, wsK, wsVt,
                                                 labels, lemb);
    attn_fwd<<<dim3(16, 32), 256, 0, stream>>>(wsQ, wsK, wsVt, wsAO);
    gemm_out<<<dim3(8, 64), 256, 0, stream>>>(wsAO, WoB, bo, out);
}